// Round 7
// baseline (623.447 us; speedup 1.0000x reference)
//
#include <hip/hip_runtime.h>

#define EPS 1e-5f
#define SLOPE 0.2f

// Copy-free LayerNorm + LeakyReLU over N register-resident elements.
template<int N>
__device__ __forceinline__ void ln_lrelu(float* h, const float* __restrict__ g,
                                         const float* __restrict__ b) {
  float m, v;
  if constexpr (N >= 4) {
    float s0 = 0.f, s1 = 0.f, s2 = 0.f, s3 = 0.f;
#pragma unroll
    for (int j = 0; j < N; j += 4) {
      s0 += h[j]; s1 += h[j + 1]; s2 += h[j + 2]; s3 += h[j + 3];
    }
    m = ((s0 + s1) + (s2 + s3)) * (1.0f / N);
    float v0 = 0.f, v1 = 0.f, v2 = 0.f, v3 = 0.f;
#pragma unroll
    for (int j = 0; j < N; j += 4) {
      float d0 = h[j] - m, d1 = h[j + 1] - m, d2 = h[j + 2] - m, d3 = h[j + 3] - m;
      v0 = fmaf(d0, d0, v0); v1 = fmaf(d1, d1, v1);
      v2 = fmaf(d2, d2, v2); v3 = fmaf(d3, d3, v3);
    }
    v = ((v0 + v1) + (v2 + v3)) * (1.0f / N);
  } else {
    float s = 0.f;
#pragma unroll
    for (int j = 0; j < N; ++j) s += h[j];
    m = s * (1.0f / N);
    float vv = 0.f;
#pragma unroll
    for (int j = 0; j < N; ++j) { float d = h[j] - m; vv = fmaf(d, d, vv); }
    v = vv * (1.0f / N);
  }
  float rs = rsqrtf(v + EPS);
#pragma unroll
  for (int j = 0; j < N; ++j) {
    float t = (h[j] - m) * rs * g[j] + b[j];
    h[j] = fmaxf(t, SLOPE * t);   // LeakyReLU(0.2), exact for both signs
  }
}

template<int DIN, int DOUT>
__device__ __forceinline__ void linear(const float* hin, float* hout,
                                       const float* __restrict__ W) {
#pragma unroll
  for (int j = 0; j < DOUT; ++j) hout[j] = 0.f;
#pragma unroll
  for (int k = 0; k < DIN; ++k) {
    float hk = hin[k];
#pragma unroll
    for (int j = 0; j < DOUT; ++j) hout[j] = fmaf(hk, W[k * DOUT + j], hout[j]);
  }
}

// Consume 16 x-columns (4 float4) against W1 rows starting at W1base.
__device__ __forceinline__ void consume16(const float4* buf,
                                          const float* __restrict__ W1base,
                                          float* h1) {
#pragma unroll
  for (int q = 0; q < 4; ++q) {
#pragma unroll
    for (int kk = 0; kk < 4; ++kk) {
      float xk = (kk == 0) ? buf[q].x : (kk == 1) ? buf[q].y
               : (kk == 2) ? buf[q].z : buf[q].w;
      const float* __restrict__ wr = W1base + (q * 4 + kk) * 32;
#pragma unroll
      for (int j = 0; j < 32; ++j) h1[j] = fmaf(xk, wr[j], h1[j]);
    }
  }
}

__global__ __launch_bounds__(256) void disc_fused(
    const float* __restrict__ x,
    const float* __restrict__ W1, const float* __restrict__ g1, const float* __restrict__ b1,
    const float* __restrict__ W2, const float* __restrict__ g2, const float* __restrict__ b2,
    const float* __restrict__ W3, const float* __restrict__ g3, const float* __restrict__ b3,
    const float* __restrict__ W4, const float* __restrict__ g4, const float* __restrict__ b4,
    const float* __restrict__ W5, const float* __restrict__ g5, const float* __restrict__ b5,
    const float* __restrict__ W6, const float* __restrict__ g6, const float* __restrict__ b6,
    const float* __restrict__ W7, const float* __restrict__ g7, const float* __restrict__ b7,
    const float* __restrict__ W8, const float* __restrict__ b8,
    float* __restrict__ out, int nrows) {
  const int tid = threadIdx.x;
  const int w = tid >> 6;                       // wave id 0..3 (wave-uniform)
  const long row = (long)blockIdx.x * 256 + tid;
  if (row >= (long)nrows) return;

  // ---- Layer 1 (128->32): direct per-thread row loads, ping-pong pipelined.
  // WAVE-STAGGERED traversal: wave w starts at 16-col chunk (2w)&7 and wraps.
  // h1 accumulation is commutative, so the result is identical; but the 4
  // waves (and phase-drifted blocks) touch disjoint weight regions at any
  // instant -> scalar weight-cache misses overlap instead of serializing.
  const float4* __restrict__ xr4 = reinterpret_cast<const float4*>(x) + row * 32;
  const int c0 = (w & 3) * 2;                   // starting chunk 0,2,4,6

  float h1[32];
#pragma unroll
  for (int j = 0; j < 32; ++j) h1[j] = 0.f;

  float4 A[4], B[4];
  {
    const int i0 = c0 & 7, i1 = (c0 + 1) & 7;
#pragma unroll
    for (int q = 0; q < 4; ++q) A[q] = xr4[i0 * 4 + q];
#pragma unroll
    for (int q = 0; q < 4; ++q) B[q] = xr4[i1 * 4 + q];
  }

#pragma unroll 1
  for (int bb = 0; bb < 3; ++bb) {
    const int ia = (c0 + 2 * bb) & 7;           // chunk being consumed from A
    const int ib = (c0 + 2 * bb + 1) & 7;       // chunk being consumed from B
    const int ina = (c0 + 2 * bb + 2) & 7;      // next chunk -> A
    const int inb = (c0 + 2 * bb + 3) & 7;      // next chunk -> B
    consume16(A, W1 + ia * 16 * 32, h1);
#pragma unroll
    for (int q = 0; q < 4; ++q) A[q] = xr4[ina * 4 + q];
    consume16(B, W1 + ib * 16 * 32, h1);
#pragma unroll
    for (int q = 0; q < 4; ++q) B[q] = xr4[inb * 4 + q];
  }
  {
    const int ia = (c0 + 6) & 7, ib = (c0 + 7) & 7;
    consume16(A, W1 + ia * 16 * 32, h1);
    consume16(B, W1 + ib * 16 * 32, h1);
  }
  ln_lrelu<32>(h1, g1, b1);

  // ---- Layer 2 (32->64) streamed: h2 never register-resident. ----
  // jb-blocks traversed in wave-staggered order (commutative sums).
  const int jbo = (w & 3) * 4;                  // starting jb block 0,4,8,12

  // Pass 1: LN stats via E[x^2]-m^2 (EPS floors the variance -> safe).
  float sum2 = 0.f, sq2 = 0.f;
#pragma unroll 1
  for (int jb = 0; jb < 16; ++jb) {
    const int jbe = (jb + jbo) & 15;
    float a0 = 0.f, a1 = 0.f, a2 = 0.f, a3 = 0.f;
#pragma unroll
    for (int k = 0; k < 32; ++k) {
      const float* __restrict__ wr = &W2[k * 64 + jbe * 4];
      a0 = fmaf(h1[k], wr[0], a0);
      a1 = fmaf(h1[k], wr[1], a1);
      a2 = fmaf(h1[k], wr[2], a2);
      a3 = fmaf(h1[k], wr[3], a3);
    }
    sum2 += (a0 + a1) + (a2 + a3);
    sq2 = fmaf(a0, a0, sq2); sq2 = fmaf(a1, a1, sq2);
    sq2 = fmaf(a2, a2, sq2); sq2 = fmaf(a3, a3, sq2);
  }
  const float m2 = sum2 * (1.0f / 64.0f);
  const float v2 = fmaf(-m2, m2, sq2 * (1.0f / 64.0f));
  const float rs2 = rsqrtf(v2 + EPS);

  // Pass 2: recompute h2 block, LN+LeakyReLU, fuse straight into h3 accum.
  float h3[32];
#pragma unroll
  for (int i = 0; i < 32; ++i) h3[i] = 0.f;
#pragma unroll 1
  for (int jb = 0; jb < 16; ++jb) {
    const int jbe = (jb + jbo) & 15;
    float a0 = 0.f, a1 = 0.f, a2 = 0.f, a3 = 0.f;
#pragma unroll
    for (int k = 0; k < 32; ++k) {
      const float* __restrict__ wr = &W2[k * 64 + jbe * 4];
      a0 = fmaf(h1[k], wr[0], a0);
      a1 = fmaf(h1[k], wr[1], a1);
      a2 = fmaf(h1[k], wr[2], a2);
      a3 = fmaf(h1[k], wr[3], a3);
    }
#pragma unroll
    for (int u = 0; u < 4; ++u) {
      float a = (u == 0) ? a0 : (u == 1) ? a1 : (u == 2) ? a2 : a3;
      int j = jbe * 4 + u;
      float y = (a - m2) * rs2 * g2[j] + b2[j];
      y = fmaxf(y, SLOPE * y);
      const float* __restrict__ wr3 = &W3[j * 32];
#pragma unroll
      for (int i = 0; i < 32; ++i) h3[i] = fmaf(y, wr3[i], h3[i]);
    }
  }
  ln_lrelu<32>(h3, g3, b3);

  float h4[16]; linear<32, 16>(h3, h4, W4); ln_lrelu<16>(h4, g4, b4);
  float h5[8];  linear<16, 8>(h4, h5, W5);  ln_lrelu<8>(h5, g5, b5);
  float h6[4];  linear<8, 4>(h5, h6, W6);   ln_lrelu<4>(h6, g6, b6);
  float h7[2];  linear<4, 2>(h6, h7, W7);   ln_lrelu<2>(h7, g7, b7);

  out[row] = fmaf(h7[1], W8[1], fmaf(h7[0], W8[0], b8[0]));
}

extern "C" void kernel_launch(void* const* d_in, const int* in_sizes, int n_in,
                              void* d_out, int out_size, void* d_ws, size_t ws_size,
                              hipStream_t stream) {
  const float* x  = (const float*)d_in[0];
  const float* W1 = (const float*)d_in[1];
  const float* g1 = (const float*)d_in[2];
  const float* b1 = (const float*)d_in[3];
  const float* W2 = (const float*)d_in[4];
  const float* g2 = (const float*)d_in[5];
  const float* b2 = (const float*)d_in[6];
  const float* W3 = (const float*)d_in[7];
  const float* g3 = (const float*)d_in[8];
  const float* b3 = (const float*)d_in[9];
  const float* W4 = (const float*)d_in[10];
  const float* g4 = (const float*)d_in[11];
  const float* b4 = (const float*)d_in[12];
  const float* W5 = (const float*)d_in[13];
  const float* g5 = (const float*)d_in[14];
  const float* b5 = (const float*)d_in[15];
  const float* W6 = (const float*)d_in[16];
  const float* g6 = (const float*)d_in[17];
  const float* b6 = (const float*)d_in[18];
  const float* W7 = (const float*)d_in[19];
  const float* g7 = (const float*)d_in[20];
  const float* b7 = (const float*)d_in[21];
  const float* W8 = (const float*)d_in[22];
  const float* b8 = (const float*)d_in[23];
  float* out = (float*)d_out;

  const int nrows = in_sizes[0] / 128;          // 524288
  const int grid = (nrows + 255) / 256;         // 2048
  hipLaunchKernelGGL(disc_fused, dim3(grid), dim3(256), 0, stream,
                     x, W1, g1, b1, W2, g2, b2, W3, g3, b3, W4, g4, b4,
                     W5, g5, b5, W6, g6, b6, W7, g7, b7, W8, b8, out, nrows);
}

// Round 8
// 151.925 us; speedup vs baseline: 4.1037x; 4.1037x over previous
//
#include <hip/hip_runtime.h>

#define EPS 1e-5f
#define SLOPE 0.2f

typedef float v2f __attribute__((ext_vector_type(2)));

// packed fma: (s,s)*w + a  -> v_pk_fma_f32 (op_sel broadcast) when available
__device__ __forceinline__ v2f pkfma(float s, v2f w, v2f a) {
  v2f sv = {s, s};
  return __builtin_elementwise_fma(sv, w, a);
}

// LayerNorm + LeakyReLU over 2*N2 elements held as N2 packed float2.
template<int N2>
__device__ __forceinline__ void ln_lrelu_pk(v2f* h, const float* __restrict__ g,
                                            const float* __restrict__ b) {
  const v2f* g2 = reinterpret_cast<const v2f*>(g);
  const v2f* b2 = reinterpret_cast<const v2f*>(b);
  const float invN = 1.0f / (2 * N2);
  float m, vv;
  if constexpr (N2 >= 2) {
    v2f s0 = {0.f, 0.f}, s1 = {0.f, 0.f};
#pragma unroll
    for (int j = 0; j < N2; j += 2) { s0 += h[j]; s1 += h[j + 1]; }
    v2f st = s0 + s1;
    m = (st.x + st.y) * invN;
    v2f q0 = {0.f, 0.f}, q1 = {0.f, 0.f};
#pragma unroll
    for (int j = 0; j < N2; j += 2) {
      v2f d0 = h[j] - m, d1 = h[j + 1] - m;
      q0 = __builtin_elementwise_fma(d0, d0, q0);
      q1 = __builtin_elementwise_fma(d1, d1, q1);
    }
    v2f qt = q0 + q1;
    vv = (qt.x + qt.y) * invN;
  } else {
    m = (h[0].x + h[0].y) * 0.5f;
    float dx = h[0].x - m, dy = h[0].y - m;
    vv = (dx * dx + dy * dy) * 0.5f;
  }
  const float rs = rsqrtf(vv + EPS);
#pragma unroll
  for (int j = 0; j < N2; ++j) {
    v2f t = (h[j] - m) * rs * g2[j] + b2[j];
    h[j] = __builtin_elementwise_max(t, SLOPE * t);
  }
}

// hout (DOUT2 packed) = hin (DIN scalars, packed storage) * W[DIN][2*DOUT2]
template<int DIN, int DOUT2>
__device__ __forceinline__ void linear_pk(const v2f* hin, v2f* hout,
                                          const float* __restrict__ W) {
#pragma unroll
  for (int j = 0; j < DOUT2; ++j) hout[j] = (v2f){0.f, 0.f};
#pragma unroll
  for (int k = 0; k < DIN; ++k) {
    float hk = (k & 1) ? hin[k >> 1].y : hin[k >> 1].x;
    const v2f* wr = reinterpret_cast<const v2f*>(W + k * (DOUT2 * 2));
#pragma unroll
    for (int j = 0; j < DOUT2; ++j) hout[j] = pkfma(hk, wr[j], hout[j]);
  }
}

__global__ __launch_bounds__(256) void disc_fused(
    const float* __restrict__ x,
    const float* __restrict__ W1, const float* __restrict__ g1, const float* __restrict__ b1,
    const float* __restrict__ W2, const float* __restrict__ g2, const float* __restrict__ b2,
    const float* __restrict__ W3, const float* __restrict__ g3, const float* __restrict__ b3,
    const float* __restrict__ W4, const float* __restrict__ g4, const float* __restrict__ b4,
    const float* __restrict__ W5, const float* __restrict__ g5, const float* __restrict__ b5,
    const float* __restrict__ W6, const float* __restrict__ g6, const float* __restrict__ b6,
    const float* __restrict__ W7, const float* __restrict__ g7, const float* __restrict__ b7,
    const float* __restrict__ W8, const float* __restrict__ b8,
    float* __restrict__ out, int nrows) {
  const long row = (long)blockIdx.x * 256 + threadIdx.x;
  if (row >= (long)nrows) return;

  // ---- Layer 1 (128->32): direct per-thread row loads (R3 pattern),
  // weights on the scalar path, FMAs packed 2-wide over the j dimension.
  const float4* __restrict__ xr4 = reinterpret_cast<const float4*>(x) + row * 32;
  v2f h1[16];
#pragma unroll
  for (int j = 0; j < 16; ++j) h1[j] = (v2f){0.f, 0.f};

#pragma unroll 1           // one 8-load burst (32 VGPR) in flight at a time
  for (int cc = 0; cc < 4; ++cc) {
    float4 bv[8];
#pragma unroll
    for (int q = 0; q < 8; ++q) bv[q] = xr4[cc * 8 + q];
#pragma unroll
    for (int q = 0; q < 8; ++q) {
#pragma unroll
      for (int kk = 0; kk < 4; ++kk) {
        float xk = (kk == 0) ? bv[q].x : (kk == 1) ? bv[q].y
                 : (kk == 2) ? bv[q].z : bv[q].w;
        const v2f* wr =
            reinterpret_cast<const v2f*>(W1 + (cc * 32 + q * 4 + kk) * 32);
#pragma unroll
        for (int j = 0; j < 16; ++j) h1[j] = pkfma(xk, wr[j], h1[j]);
      }
    }
  }
  ln_lrelu_pk<16>(h1, g1, b1);

  // ---- Layer 2 (32->64) streamed: h2 never register-resident. ----
  const v2f* W2v = reinterpret_cast<const v2f*>(W2);

  // Pass 1: LN stats via E[x^2]-m^2 (EPS floors the variance -> safe).
  float sum2 = 0.f, sq2 = 0.f;
#pragma unroll 1
  for (int jb = 0; jb < 16; ++jb) {
    v2f a01 = {0.f, 0.f}, a23 = {0.f, 0.f};
#pragma unroll
    for (int k = 0; k < 32; ++k) {
      float hk = (k & 1) ? h1[k >> 1].y : h1[k >> 1].x;
      a01 = pkfma(hk, W2v[k * 32 + jb * 2], a01);
      a23 = pkfma(hk, W2v[k * 32 + jb * 2 + 1], a23);
    }
    sum2 += (a01.x + a01.y) + (a23.x + a23.y);
    sq2 = fmaf(a01.x, a01.x, sq2); sq2 = fmaf(a01.y, a01.y, sq2);
    sq2 = fmaf(a23.x, a23.x, sq2); sq2 = fmaf(a23.y, a23.y, sq2);
  }
  const float m2 = sum2 * (1.0f / 64.0f);
  const float v2 = fmaf(-m2, m2, sq2 * (1.0f / 64.0f));
  const float rs2 = rsqrtf(v2 + EPS);

  // Pass 2: recompute h2 block, LN+LeakyReLU, fuse straight into h3 accum.
  v2f h3[16];
#pragma unroll
  for (int i = 0; i < 16; ++i) h3[i] = (v2f){0.f, 0.f};
#pragma unroll 1
  for (int jb = 0; jb < 16; ++jb) {
    v2f a01 = {0.f, 0.f}, a23 = {0.f, 0.f};
#pragma unroll
    for (int k = 0; k < 32; ++k) {
      float hk = (k & 1) ? h1[k >> 1].y : h1[k >> 1].x;
      a01 = pkfma(hk, W2v[k * 32 + jb * 2], a01);
      a23 = pkfma(hk, W2v[k * 32 + jb * 2 + 1], a23);
    }
#pragma unroll
    for (int u = 0; u < 4; ++u) {
      float a = (u == 0) ? a01.x : (u == 1) ? a01.y : (u == 2) ? a23.x : a23.y;
      int j = jb * 4 + u;
      float y = (a - m2) * rs2 * g2[j] + b2[j];
      y = fmaxf(y, SLOPE * y);
      const v2f* wr3 = reinterpret_cast<const v2f*>(W3 + j * 32);
#pragma unroll
      for (int i = 0; i < 16; ++i) h3[i] = pkfma(y, wr3[i], h3[i]);
    }
  }
  ln_lrelu_pk<16>(h3, g3, b3);

  v2f h4[8]; linear_pk<32, 8>(h3, h4, W4); ln_lrelu_pk<8>(h4, g4, b4);
  v2f h5[4]; linear_pk<16, 4>(h4, h5, W5); ln_lrelu_pk<4>(h5, g5, b5);
  v2f h6[2]; linear_pk<8, 2>(h5, h6, W6);  ln_lrelu_pk<2>(h6, g6, b6);
  v2f h7[1]; linear_pk<4, 1>(h6, h7, W7);  ln_lrelu_pk<1>(h7, g7, b7);

  out[row] = fmaf(h7[0].y, W8[1], fmaf(h7[0].x, W8[0], b8[0]));
}

extern "C" void kernel_launch(void* const* d_in, const int* in_sizes, int n_in,
                              void* d_out, int out_size, void* d_ws, size_t ws_size,
                              hipStream_t stream) {
  const float* x  = (const float*)d_in[0];
  const float* W1 = (const float*)d_in[1];
  const float* g1 = (const float*)d_in[2];
  const float* b1 = (const float*)d_in[3];
  const float* W2 = (const float*)d_in[4];
  const float* g2 = (const float*)d_in[5];
  const float* b2 = (const float*)d_in[6];
  const float* W3 = (const float*)d_in[7];
  const float* g3 = (const float*)d_in[8];
  const float* b3 = (const float*)d_in[9];
  const float* W4 = (const float*)d_in[10];
  const float* g4 = (const float*)d_in[11];
  const float* b4 = (const float*)d_in[12];
  const float* W5 = (const float*)d_in[13];
  const float* g5 = (const float*)d_in[14];
  const float* b5 = (const float*)d_in[15];
  const float* W6 = (const float*)d_in[16];
  const float* g6 = (const float*)d_in[17];
  const float* b6 = (const float*)d_in[18];
  const float* W7 = (const float*)d_in[19];
  const float* g7 = (const float*)d_in[20];
  const float* b7 = (const float*)d_in[21];
  const float* W8 = (const float*)d_in[22];
  const float* b8 = (const float*)d_in[23];
  float* out = (float*)d_out;

  const int nrows = in_sizes[0] / 128;          // 524288
  const int grid = (nrows + 255) / 256;         // 2048
  hipLaunchKernelGGL(disc_fused, dim3(grid), dim3(256), 0, stream,
                     x, W1, g1, b1, W2, g2, b2, W3, g3, b3, W4, g4, b4,
                     W5, g5, b5, W6, g6, b6, W7, g7, b7, W8, b8, out, nrows);
}